// Round 2
// baseline (147.514 us; speedup 1.0000x reference)
//
#include <hip/hip_runtime.h>
#include <hip/hip_bf16.h>

#define B_   8
#define N_   128
#define H_   768
#define HID_ 384
#define L_   100

typedef float f32x4 __attribute__((ext_vector_type(4)));
typedef short s16x8 __attribute__((ext_vector_type(8)));

__device__ __forceinline__ short f2bf(float f) {
    __hip_bfloat16 h = __float2bfloat16(f);
    return __builtin_bit_cast(short, h);
}

// ---------------------------------------------------------------------------
// Prep: swizzle W1 (1536x384 fp32) into MFMA-B fragment layout, bf16.
// Layout: W1f[ct 0..47][kk 0..23][lane 0..63][e 0..7]
//   col c = ct*16 + (lane&15)   (c<384 -> W1_row col c ; else W1_col col c-384)
//   k     = kk*32 + (lane>>4)*8 + e
// ---------------------------------------------------------------------------
__global__ void prep_w1f(const float* __restrict__ W1, short* __restrict__ W1f) {
    int tid = blockIdx.x * 256 + threadIdx.x;
    if (tid >= 48 * 24 * 64) return;
    int lane = tid & 63;
    int kk   = (tid >> 6) % 24;
    int ct   = tid / (24 * 64);
    int c    = ct * 16 + (lane & 15);
    int k0   = kk * 32 + ((lane >> 4) << 3);
    short v[8];
#pragma unroll
    for (int e = 0; e < 8; ++e) {
        int k = k0 + e;
        float f = (c < HID_) ? W1[(size_t)k * HID_ + c]
                             : W1[(size_t)(H_ + k) * HID_ + (c - HID_)];
        v[e] = f2bf(f);
    }
    ((s16x8*)W1f)[tid] = *(const s16x8*)v;
}

// ---------------------------------------------------------------------------
// Prep: swizzle W2 (384x100 fp32) into MFMA-B fragment layout, bf16, L padded
// to 112.  Layout: W2f[kk 0..11][t 0..6][lane][e]
// ---------------------------------------------------------------------------
__global__ void prep_w2f(const float* __restrict__ W2, short* __restrict__ W2f) {
    int tid = blockIdx.x * 256 + threadIdx.x;
    if (tid >= 12 * 7 * 64) return;
    int lane = tid & 63;
    int t    = (tid >> 6) % 7;
    int kk   = tid / (7 * 64);
    int c    = t * 16 + (lane & 15);
    int k0   = kk * 32 + ((lane >> 4) << 3);
    short v[8];
#pragma unroll
    for (int e = 0; e < 8; ++e) {
        float f = (c < L_) ? W2[(size_t)(k0 + e) * L_ + c] : 0.0f;
        v[e] = f2bf(f);
    }
    ((s16x8*)W2f)[tid] = *(const s16x8*)v;
}

// ---------------------------------------------------------------------------
// P = repr @ W1_row + b1 (1024x384), Q = repr @ W1_col (1024x384)
// Grid 768 blocks: blk = rt*12 + cg_grp; wave w -> col-tile ct = cg_grp*4 + w.
// All 4 waves of a block share the same 16 A-rows (L1 reuse).
// ---------------------------------------------------------------------------
__global__ __launch_bounds__(256) void pq_gemm(
    const float* __restrict__ repr, const short* __restrict__ W1f,
    const float* __restrict__ b1,
    float* __restrict__ P, float* __restrict__ Q)
{
    const int blk  = blockIdx.x;
    const int rt   = blk / 12;
    const int w    = threadIdx.x >> 6;
    const int ct   = (blk % 12) * 4 + w;
    const int lane = threadIdx.x & 63;
    const int l15  = lane & 15;
    const int g    = lane >> 4;

    f32x4 acc;
    acc[0] = 0.f; acc[1] = 0.f; acc[2] = 0.f; acc[3] = 0.f;

    const float* aptr  = repr + (size_t)(rt * 16 + l15) * H_ + (g << 3);
    const s16x8* bbase = (const s16x8*)W1f + (size_t)(ct * 24) * 64 + lane;

#pragma unroll 4
    for (int kk = 0; kk < 24; ++kk) {
        float a[8];
        *(float4*)&a[0] = *(const float4*)(aptr + kk * 32);
        *(float4*)&a[4] = *(const float4*)(aptr + kk * 32 + 4);
        s16x8 af;
#pragma unroll
        for (int e = 0; e < 8; ++e) af[e] = f2bf(a[e]);
        s16x8 bf = bbase[(size_t)kk * 64];
        acc = __builtin_amdgcn_mfma_f32_16x16x32_bf16(af, bf, acc, 0, 0, 0);
    }

    const int r0 = rt * 16 + (g << 2);
    const int c  = ct * 16 + l15;
#pragma unroll
    for (int r = 0; r < 4; ++r) {
        int row = r0 + r;
        float v = acc[r];
        if (c < HID_) P[(size_t)row * HID_ + c] = v + b1[c];
        else          Q[(size_t)row * HID_ + (c - HID_)] = v;
    }
}

// ---------------------------------------------------------------------------
// Main fused kernel: out[b,i,j,l] = relu(P[b,j,:]+Q[b,i,:]) . W2 + b2
// Grid 1024: blk = b*128 + ip*2 + jh. Block = (b, 2 i-values, 64 j-values).
// Wave w owns j-tile [jh*64 + w*16, +16). acc[2 i][7 l-tiles].
// Fully unrolled K with 1-deep register prefetch of P/Q slices.
// ---------------------------------------------------------------------------
__global__ __launch_bounds__(256, 4) void fused_out(
    const float* __restrict__ P, const float* __restrict__ Q,
    const short* __restrict__ W2f, const float* __restrict__ b2,
    float* __restrict__ out)
{
    const int blk  = blockIdx.x;
    const int b    = blk >> 7;
    const int rem  = blk & 127;
    const int i0   = (rem >> 1) << 1;          // ip*2
    const int jh   = rem & 1;
    const int w    = threadIdx.x >> 6;
    const int lane = threadIdx.x & 63;
    const int l15  = lane & 15;
    const int g    = lane >> 4;
    const int j0   = jh * 64 + w * 16;

    const float* __restrict__ prow = P + ((size_t)(b * N_) + j0 + l15) * HID_ + (g << 3);
    const float* __restrict__ q0p  = Q + (size_t)(b * N_ + i0) * HID_ + (g << 3);
    const float* __restrict__ q1p  = q0p + HID_;

    f32x4 acc[2][7];
#pragma unroll
    for (int ii = 0; ii < 2; ++ii)
#pragma unroll
        for (int t = 0; t < 7; ++t) {
            acc[ii][t][0] = 0.f; acc[ii][t][1] = 0.f;
            acc[ii][t][2] = 0.f; acc[ii][t][3] = 0.f;
        }

    // software-pipelined load buffers (kk slice = 32 floats, lane takes 8)
    float4 lp0  = *(const float4*)(prow);
    float4 lp1  = *(const float4*)(prow + 4);
    float4 lq00 = *(const float4*)(q0p);
    float4 lq01 = *(const float4*)(q0p + 4);
    float4 lq10 = *(const float4*)(q1p);
    float4 lq11 = *(const float4*)(q1p + 4);

#pragma unroll
    for (int kk = 0; kk < 12; ++kk) {
        float p[8], q0v[8], q1v[8];
        *(float4*)&p[0]   = lp0;  *(float4*)&p[4]   = lp1;
        *(float4*)&q0v[0] = lq00; *(float4*)&q0v[4] = lq01;
        *(float4*)&q1v[0] = lq10; *(float4*)&q1v[4] = lq11;

        if (kk < 11) {
            const int d = (kk + 1) * 32;
            lp0  = *(const float4*)(prow + d);
            lp1  = *(const float4*)(prow + d + 4);
            lq00 = *(const float4*)(q0p + d);
            lq01 = *(const float4*)(q0p + d + 4);
            lq10 = *(const float4*)(q1p + d);
            lq11 = *(const float4*)(q1p + d + 4);
        }

        s16x8 af0, af1;
#pragma unroll
        for (int e = 0; e < 8; ++e) {
            af0[e] = f2bf(fmaxf(p[e] + q0v[e], 0.f));
            af1[e] = f2bf(fmaxf(p[e] + q1v[e], 0.f));
        }

        const s16x8* bfp = (const s16x8*)W2f + (size_t)(kk * 7) * 64 + lane;
#pragma unroll
        for (int t = 0; t < 7; ++t) {
            s16x8 bf = bfp[(size_t)t * 64];
            acc[0][t] = __builtin_amdgcn_mfma_f32_16x16x32_bf16(af0, bf, acc[0][t], 0, 0, 0);
            acc[1][t] = __builtin_amdgcn_mfma_f32_16x16x32_bf16(af1, bf, acc[1][t], 0, 0, 0);
        }
    }

    float bias[7];
#pragma unroll
    for (int t = 0; t < 7; ++t) {
        int l = t * 16 + l15;
        bias[t] = (l < L_) ? b2[l] : 0.f;
    }

#pragma unroll
    for (int ii = 0; ii < 2; ++ii) {
        const size_t obase = (size_t)(b * N_ + (i0 + ii)) * N_ * L_;
#pragma unroll
        for (int r = 0; r < 4; ++r) {
            int j = j0 + (g << 2) + r;
            float* op = out + obase + (size_t)j * L_;
#pragma unroll
            for (int t = 0; t < 7; ++t) {
                int l = t * 16 + l15;
                if (l < L_) __builtin_nontemporal_store(acc[ii][t][r] + bias[t], op + l);
            }
        }
    }
}

// ---------------------------------------------------------------------------
extern "C" void kernel_launch(void* const* d_in, const int* in_sizes, int n_in,
                              void* d_out, int out_size, void* d_ws, size_t ws_size,
                              hipStream_t stream)
{
    const float* repr = (const float*)d_in[0];
    const float* W1   = (const float*)d_in[1];
    const float* b1   = (const float*)d_in[2];
    const float* W2   = (const float*)d_in[3];
    const float* b2   = (const float*)d_in[4];
    float* out = (float*)d_out;

    char* ws = (char*)d_ws;
    float* P   = (float*)(ws);                         // 1572864 B
    float* Qm  = (float*)(ws + 1572864);               // 1572864 B
    short* W1f = (short*)(ws + 3145728);               // 1179648 B
    short* W2f = (short*)(ws + 3145728 + 1179648);     // 86016 B

    hipLaunchKernelGGL(prep_w1f,  dim3(288),  dim3(256), 0, stream, W1, W1f);
    hipLaunchKernelGGL(prep_w2f,  dim3(21),   dim3(256), 0, stream, W2, W2f);
    hipLaunchKernelGGL(pq_gemm,   dim3(768),  dim3(256), 0, stream, repr, W1f, b1, P, Qm);
    hipLaunchKernelGGL(fused_out, dim3(1024), dim3(256), 0, stream, P, Qm, W2f, b2, out);
}

// Round 3
// 143.599 us; speedup vs baseline: 1.0273x; 1.0273x over previous
//
#include <hip/hip_runtime.h>
#include <hip/hip_bf16.h>

#define B_   8
#define N_   128
#define H_   768
#define HID_ 384
#define L_   100

typedef float f32x4 __attribute__((ext_vector_type(4)));
typedef short s16x8 __attribute__((ext_vector_type(8)));

__device__ __forceinline__ short f2bf(float f) {
    __hip_bfloat16 h = __float2bfloat16(f);
    return __builtin_bit_cast(short, h);
}

// ---------------------------------------------------------------------------
// Prep: swizzle W1 (1536x384 fp32) into MFMA-B fragment layout, bf16.
// W1f[ct 0..47][kk 0..23][lane][e]: col c = ct*16+(lane&15), k = kk*32+(lane>>4)*8+e
// ---------------------------------------------------------------------------
__global__ void prep_w1f(const float* __restrict__ W1, short* __restrict__ W1f) {
    int tid = blockIdx.x * 256 + threadIdx.x;
    if (tid >= 48 * 24 * 64) return;
    int lane = tid & 63;
    int kk   = (tid >> 6) % 24;
    int ct   = tid / (24 * 64);
    int c    = ct * 16 + (lane & 15);
    int k0   = kk * 32 + ((lane >> 4) << 3);
    short v[8];
#pragma unroll
    for (int e = 0; e < 8; ++e) {
        int k = k0 + e;
        float f = (c < HID_) ? W1[(size_t)k * HID_ + c]
                             : W1[(size_t)(H_ + k) * HID_ + (c - HID_)];
        v[e] = f2bf(f);
    }
    ((s16x8*)W1f)[tid] = *(const s16x8*)v;
}

// ---------------------------------------------------------------------------
// Prep: swizzle W2 (384x100 fp32) into MFMA-B fragments, bf16, L padded to 112.
// W2f[kk 0..11][t 0..6][lane][e]
// ---------------------------------------------------------------------------
__global__ void prep_w2f(const float* __restrict__ W2, short* __restrict__ W2f) {
    int tid = blockIdx.x * 256 + threadIdx.x;
    if (tid >= 12 * 7 * 64) return;
    int lane = tid & 63;
    int t    = (tid >> 6) % 7;
    int kk   = tid / (7 * 64);
    int c    = t * 16 + (lane & 15);
    int k0   = kk * 32 + ((lane >> 4) << 3);
    short v[8];
#pragma unroll
    for (int e = 0; e < 8; ++e) {
        float f = (c < L_) ? W2[(size_t)(k0 + e) * L_ + c] : 0.0f;
        v[e] = f2bf(f);
    }
    ((s16x8*)W2f)[tid] = *(const s16x8*)v;
}

// ---------------------------------------------------------------------------
// P = repr @ W1_row + b1 (1024x384), Q = repr @ W1_col (1024x384)
// Grid 768: blk = rt*12 + cg; wave w -> ct = cg*4 + w. 4 waves share A-rows.
// ---------------------------------------------------------------------------
__global__ __launch_bounds__(256) void pq_gemm(
    const float* __restrict__ repr, const short* __restrict__ W1f,
    const float* __restrict__ b1,
    float* __restrict__ P, float* __restrict__ Q)
{
    const int blk  = blockIdx.x;
    const int rt   = blk / 12;
    const int w    = threadIdx.x >> 6;
    const int ct   = (blk % 12) * 4 + w;
    const int lane = threadIdx.x & 63;
    const int l15  = lane & 15;
    const int g    = lane >> 4;

    f32x4 acc;
    acc[0] = 0.f; acc[1] = 0.f; acc[2] = 0.f; acc[3] = 0.f;

    const float* aptr  = repr + (size_t)(rt * 16 + l15) * H_ + (g << 3);
    const s16x8* bbase = (const s16x8*)W1f + (size_t)(ct * 24) * 64 + lane;

#pragma unroll 4
    for (int kk = 0; kk < 24; ++kk) {
        float a[8];
        *(float4*)&a[0] = *(const float4*)(aptr + kk * 32);
        *(float4*)&a[4] = *(const float4*)(aptr + kk * 32 + 4);
        s16x8 af;
#pragma unroll
        for (int e = 0; e < 8; ++e) af[e] = f2bf(a[e]);
        s16x8 bf = bbase[(size_t)kk * 64];
        acc = __builtin_amdgcn_mfma_f32_16x16x32_bf16(af, bf, acc, 0, 0, 0);
    }

    const int r0 = rt * 16 + (g << 2);
    const int c  = ct * 16 + l15;
#pragma unroll
    for (int r = 0; r < 4; ++r) {
        int row = r0 + r;
        float v = acc[r];
        if (c < HID_) P[(size_t)row * HID_ + c] = v + b1[c];
        else          Q[(size_t)row * HID_ + (c - HID_)] = v;
    }
}

// ---------------------------------------------------------------------------
// Main fused kernel: out[b,i,j,l] = relu(P[b,j,:]+Q[b,i,:]) . W2 + b2
// Grid 256 (1 block/CU), 1024 threads = 16 waves, dyn LDS = 86016 B (all W2f).
// Block = (b = blk>>5, i base = (blk&31)*4). Wave w: i0 = ibase + (w>>3)*2,
// j-tile = (w&7). W2f staged to LDS once; main loop barrier-free, B-fragments
// via ds_read_b128 (kills the per-kk L2 latency chain that capped R1/R2).
// ---------------------------------------------------------------------------
__global__ __launch_bounds__(1024, 4) void fused_out(
    const float* __restrict__ P, const float* __restrict__ Q,
    const short* __restrict__ W2f, const float* __restrict__ b2,
    float* __restrict__ out)
{
    extern __shared__ char smem[];
    s16x8* w2s = (s16x8*)smem;            // [84 chunks][64 lanes]

    const int tid  = threadIdx.x;
    const int blk  = blockIdx.x;
    const int b    = blk >> 5;
    const int ib   = (blk & 31) << 2;     // 4 i-values per block
    const int w    = tid >> 6;            // 16 waves
    const int lane = tid & 63;
    const int l15  = lane & 15;
    const int g    = lane >> 4;
    const int i0   = ib + ((w >> 3) << 1);   // 2 i per wave
    const int j0   = (w & 7) << 4;           // 16 j per wave

    // ---- stage all of W2f into LDS (84 KiB), once ----
    const s16x8* w2g = (const s16x8*)W2f;
    for (int c = w; c < 84; c += 16)
        w2s[c * 64 + lane] = w2g[c * 64 + lane];
    __syncthreads();

    const float* __restrict__ prow = P + ((size_t)(b * N_) + j0 + l15) * HID_ + (g << 3);
    const float* __restrict__ q0p  = Q + (size_t)(b * N_ + i0) * HID_ + (g << 3);
    const float* __restrict__ q1p  = q0p + HID_;

    f32x4 acc[2][7];
#pragma unroll
    for (int ii = 0; ii < 2; ++ii)
#pragma unroll
        for (int t = 0; t < 7; ++t) {
            acc[ii][t][0] = 0.f; acc[ii][t][1] = 0.f;
            acc[ii][t][2] = 0.f; acc[ii][t][3] = 0.f;
        }

    // 1-deep register prefetch of the P/Q k-slices
    float4 lp0  = *(const float4*)(prow);
    float4 lp1  = *(const float4*)(prow + 4);
    float4 lq00 = *(const float4*)(q0p);
    float4 lq01 = *(const float4*)(q0p + 4);
    float4 lq10 = *(const float4*)(q1p);
    float4 lq11 = *(const float4*)(q1p + 4);

#pragma unroll
    for (int kk = 0; kk < 12; ++kk) {
        float p[8], q0v[8], q1v[8];
        *(float4*)&p[0]   = lp0;  *(float4*)&p[4]   = lp1;
        *(float4*)&q0v[0] = lq00; *(float4*)&q0v[4] = lq01;
        *(float4*)&q1v[0] = lq10; *(float4*)&q1v[4] = lq11;

        if (kk < 11) {
            const int d = (kk + 1) * 32;
            lp0  = *(const float4*)(prow + d);
            lp1  = *(const float4*)(prow + d + 4);
            lq00 = *(const float4*)(q0p + d);
            lq01 = *(const float4*)(q0p + d + 4);
            lq10 = *(const float4*)(q1p + d);
            lq11 = *(const float4*)(q1p + d + 4);
        }

        s16x8 af0, af1;
#pragma unroll
        for (int e = 0; e < 8; ++e) {
            af0[e] = f2bf(fmaxf(p[e] + q0v[e], 0.f));
            af1[e] = f2bf(fmaxf(p[e] + q1v[e], 0.f));
        }

        const s16x8* bfp = w2s + (size_t)(kk * 7) * 64 + lane;
#pragma unroll
        for (int t = 0; t < 7; ++t) {
            s16x8 bf = bfp[(size_t)t * 64];     // ds_read_b128, conflict-free linear
            acc[0][t] = __builtin_amdgcn_mfma_f32_16x16x32_bf16(af0, bf, acc[0][t], 0, 0, 0);
            acc[1][t] = __builtin_amdgcn_mfma_f32_16x16x32_bf16(af1, bf, acc[1][t], 0, 0, 0);
        }
    }

    float bias[7];
#pragma unroll
    for (int t = 0; t < 7; ++t) {
        int l = t * 16 + l15;
        bias[t] = (l < L_) ? b2[l] : 0.f;
    }

#pragma unroll
    for (int ii = 0; ii < 2; ++ii) {
        const size_t obase = (size_t)(b * N_ + (i0 + ii)) * N_ * L_;
#pragma unroll
        for (int r = 0; r < 4; ++r) {
            int j = j0 + (g << 2) + r;
            float* op = out + obase + (size_t)j * L_;
#pragma unroll
            for (int t = 0; t < 7; ++t) {
                int l = t * 16 + l15;
                if (l < L_) __builtin_nontemporal_store(acc[ii][t][r] + bias[t], op + l);
            }
        }
    }
}

// ---------------------------------------------------------------------------
extern "C" void kernel_launch(void* const* d_in, const int* in_sizes, int n_in,
                              void* d_out, int out_size, void* d_ws, size_t ws_size,
                              hipStream_t stream)
{
    const float* repr = (const float*)d_in[0];
    const float* W1   = (const float*)d_in[1];
    const float* b1   = (const float*)d_in[2];
    const float* W2   = (const float*)d_in[3];
    const float* b2   = (const float*)d_in[4];
    float* out = (float*)d_out;

    char* ws = (char*)d_ws;
    float* P   = (float*)(ws);                         // 1572864 B
    float* Qm  = (float*)(ws + 1572864);               // 1572864 B
    short* W1f = (short*)(ws + 3145728);               // 1179648 B
    short* W2f = (short*)(ws + 3145728 + 1179648);     // 86016 B

    hipLaunchKernelGGL(prep_w1f,  dim3(288), dim3(256),  0,     stream, W1, W1f);
    hipLaunchKernelGGL(prep_w2f,  dim3(21),  dim3(256),  0,     stream, W2, W2f);
    hipLaunchKernelGGL(pq_gemm,   dim3(768), dim3(256),  0,     stream, repr, W1f, b1, P, Qm);
    hipLaunchKernelGGL(fused_out, dim3(256), dim3(1024), 86016, stream, P, Qm, W2f, b2, out);
}

// Round 4
// 123.062 us; speedup vs baseline: 1.1987x; 1.1669x over previous
//
#include <hip/hip_runtime.h>
#include <hip/hip_bf16.h>

#define B_   8
#define N_   128
#define H_   768
#define HID_ 384
#define L_   100

typedef float f32x4 __attribute__((ext_vector_type(4)));
typedef short s16x8 __attribute__((ext_vector_type(8)));

__device__ __forceinline__ short f2bf(float f) {
    __hip_bfloat16 h = __float2bfloat16(f);
    return __builtin_bit_cast(short, h);
}

// async global->LDS, 16 B per lane. LDS dest = base + lane*16 (wave-uniform base);
// global src is per-lane.
__device__ __forceinline__ void gl_lds16(const void* g, void* l) {
    __builtin_amdgcn_global_load_lds(
        (const __attribute__((address_space(1))) unsigned int*)g,
        (__attribute__((address_space(3))) unsigned int*)l, 16, 0, 0);
}

// ---------------------------------------------------------------------------
// Prep: W1 (1536x384 fp32) -> MFMA-B fragments bf16.
// W1f[ct 0..47][kk 0..23][lane][e]: col c = ct*16+(lane&15), k = kk*32+(lane>>4)*8+e
// ---------------------------------------------------------------------------
__global__ void prep_w1f(const float* __restrict__ W1, short* __restrict__ W1f) {
    int tid = blockIdx.x * 256 + threadIdx.x;
    if (tid >= 48 * 24 * 64) return;
    int lane = tid & 63;
    int kk   = (tid >> 6) % 24;
    int ct   = tid / (24 * 64);
    int c    = ct * 16 + (lane & 15);
    int k0   = kk * 32 + ((lane >> 4) << 3);
    short v[8];
#pragma unroll
    for (int e = 0; e < 8; ++e) {
        int k = k0 + e;
        float f = (c < HID_) ? W1[(size_t)k * HID_ + c]
                             : W1[(size_t)(H_ + k) * HID_ + (c - HID_)];
        v[e] = f2bf(f);
    }
    ((s16x8*)W1f)[tid] = *(const s16x8*)v;
}

// ---------------------------------------------------------------------------
// Prep: W2 (384x100 fp32) -> MFMA-B fragments bf16, L padded to 112.
// W2f[kk 0..11][t 0..6][lane][e]
// ---------------------------------------------------------------------------
__global__ void prep_w2f(const float* __restrict__ W2, short* __restrict__ W2f) {
    int tid = blockIdx.x * 256 + threadIdx.x;
    if (tid >= 12 * 7 * 64) return;
    int lane = tid & 63;
    int t    = (tid >> 6) % 7;
    int kk   = tid / (7 * 64);
    int c    = t * 16 + (lane & 15);
    int k0   = kk * 32 + ((lane >> 4) << 3);
    short v[8];
#pragma unroll
    for (int e = 0; e < 8; ++e) {
        float f = (c < L_) ? W2[(size_t)(k0 + e) * L_ + c] : 0.0f;
        v[e] = f2bf(f);
    }
    ((s16x8*)W2f)[tid] = *(const s16x8*)v;
}

// ---------------------------------------------------------------------------
// pq_gemm: P(+b1) and Q from repr @ W1, MFMA.
// A (repr rows) staged to LDS via gl_lds with per-lane global addrs, stored
// unit-major [u 0..191][row 0..15] (16B units) -> conflict-free ds_read_b128.
// P written TRANSPOSED as Pt[b][slice 0..11][u 0..7][row 0..127] (16B units)
// so fused_out can stage kk-slices with fully contiguous gl_lds.
// Q written row-major [1024][384].
// Grid 768 = rt(64) x cg(12); 4 waves, wave w -> ct = cg*4+w.
// ---------------------------------------------------------------------------
__global__ __launch_bounds__(256) void pq_gemm(
    const float* __restrict__ repr, const short* __restrict__ W1f,
    const float* __restrict__ b1,
    float* __restrict__ Pt, float* __restrict__ Q)
{
    __shared__ float atile[192 * 16 * 4];   // 49152 B
    const int rt   = blockIdx.x / 12;
    const int cg   = blockIdx.x % 12;
    const int w    = threadIdx.x >> 6;
    const int lane = threadIdx.x & 63;
    const int l15  = lane & 15;
    const int g    = lane >> 4;
    const int ct   = cg * 4 + w;
    const int row_g0 = rt * 16;

    // stage 16 rows x 768 f32 = 48 KB; 48 calls (12 per wave).
    // call covers units [call*4, call*4+4) x 16 rows; lane L -> (u=call*4+(L>>4), row=L&15)
#pragma unroll
    for (int c = 0; c < 12; ++c) {
        int call = w * 12 + c;
        const float* src = repr + (size_t)(row_g0 + (lane & 15)) * H_
                         + (call * 4 + (lane >> 4)) * 4;
        gl_lds16(src, (char*)atile + call * 1024);
    }
    __syncthreads();

    f32x4 acc;
    acc[0] = 0.f; acc[1] = 0.f; acc[2] = 0.f; acc[3] = 0.f;
    const s16x8* bbase = (const s16x8*)W1f + (size_t)(ct * 24) * 64 + lane;

#pragma unroll 4
    for (int kk = 0; kk < 24; ++kk) {
        const int u0 = kk * 8 + g * 2;
        float a[8];
        *(float4*)&a[0] = *(const float4*)&atile[(u0 * 16 + l15) * 4];
        *(float4*)&a[4] = *(const float4*)&atile[((u0 + 1) * 16 + l15) * 4];
        s16x8 af;
#pragma unroll
        for (int e = 0; e < 8; ++e) af[e] = f2bf(a[e]);
        s16x8 bf = bbase[(size_t)kk * 64];
        acc = __builtin_amdgcn_mfma_f32_16x16x32_bf16(af, bf, acc, 0, 0, 0);
    }

    const int b = rt >> 3;           // 8 row-tiles per batch
    const int c = ct * 16 + l15;
#pragma unroll
    for (int r = 0; r < 4; ++r) {
        int brow = (rt & 7) * 16 + g * 4 + r;   // row within batch, 0..127
        float v = acc[r];
        if (c < HID_) {
            int slice = c >> 5, un = (c & 31) >> 2, e4 = c & 3;
            Pt[((((size_t)b * 12 + slice) * 8 + un) * 128 + brow) * 4 + e4] = v + b1[c];
        } else {
            Q[(size_t)(b * N_ + brow) * HID_ + (c - HID_)] = v;
        }
    }
}

// ---------------------------------------------------------------------------
// fused_out: out[b,i,j,l] = relu(P[b,j,:]+Q[b,i,:]) . W2 + b2
// Grid 1024: blk -> (b = blk>>7, ipair = (blk>>1)&63, jh = blk&1).
// Block 256 thr = 4 waves; wave w -> j in [jh*64+w*16, +16); 2 i per wave.
// Per kk: stage NEXT Pt slice-half (8 KB, 8 contiguous 1KB gl_lds) into the
// other LDS buffer, read current from LDS (conflict-free), af in regs,
// 14 MFMA vs W2f (L2-hot), one barrier. Q staged to LDS once.
// ---------------------------------------------------------------------------
__global__ __launch_bounds__(256) void fused_out(
    const float* __restrict__ Pt, const float* __restrict__ Q,
    const short* __restrict__ W2f, const float* __restrict__ b2,
    float* __restrict__ out)
{
    __shared__ float pbuf[2][8 * 64 * 4];   // 2 x 8192 B
    __shared__ float qlds[2 * HID_];        // 3072 B

    const int blk   = blockIdx.x;
    const int b     = blk >> 7;
    const int ipair = (blk >> 1) & 63;
    const int jh    = blk & 1;
    const int i0    = ipair * 2;
    const int w     = threadIdx.x >> 6;
    const int lane  = threadIdx.x & 63;
    const int l15   = lane & 15;
    const int g     = lane >> 4;
    const int j0    = jh * 64 + w * 16;
    const int jl0   = w * 16;               // local row base in staged half

    // ---- prologue staging ----
    if (w == 3) {
        const float* qsrc = Q + (size_t)(b * N_ + i0) * HID_;
#pragma unroll
        for (int c2 = 0; c2 < 3; ++c2)
            gl_lds16(qsrc + c2 * 256 + lane * 4, (char*)qlds + c2 * 1024);
    }
#pragma unroll
    for (int h2 = 0; h2 < 2; ++h2) {
        int u = w * 2 + h2;
        const float* src = Pt + ((((size_t)b * 12 + 0) * 8 + u) * 128 + jh * 64 + lane) * 4;
        gl_lds16(src, (char*)&pbuf[0][0] + u * 1024);
    }
    __syncthreads();

    f32x4 acc[2][7];
#pragma unroll
    for (int ii = 0; ii < 2; ++ii)
#pragma unroll
        for (int t = 0; t < 7; ++t) {
            acc[ii][t][0] = 0.f; acc[ii][t][1] = 0.f;
            acc[ii][t][2] = 0.f; acc[ii][t][3] = 0.f;
        }

#pragma unroll
    for (int kk = 0; kk < 12; ++kk) {
        const int cur = kk & 1;
        if (kk < 11) {
#pragma unroll
            for (int h2 = 0; h2 < 2; ++h2) {
                int u = w * 2 + h2;
                const float* src = Pt + ((((size_t)b * 12 + (kk + 1)) * 8 + u) * 128
                                         + jh * 64 + lane) * 4;
                gl_lds16(src, (char*)&pbuf[cur ^ 1][0] + u * 1024);
            }
        }

        float p[8], q0v[8], q1v[8];
        *(float4*)&p[0]   = *(const float4*)&pbuf[cur][((g * 2 + 0) * 64 + jl0 + l15) * 4];
        *(float4*)&p[4]   = *(const float4*)&pbuf[cur][((g * 2 + 1) * 64 + jl0 + l15) * 4];
        *(float4*)&q0v[0] = *(const float4*)&qlds[0 * HID_ + kk * 32 + g * 8];
        *(float4*)&q0v[4] = *(const float4*)&qlds[0 * HID_ + kk * 32 + g * 8 + 4];
        *(float4*)&q1v[0] = *(const float4*)&qlds[1 * HID_ + kk * 32 + g * 8];
        *(float4*)&q1v[4] = *(const float4*)&qlds[1 * HID_ + kk * 32 + g * 8 + 4];

        s16x8 af0, af1;
#pragma unroll
        for (int e = 0; e < 8; ++e) {
            af0[e] = f2bf(fmaxf(p[e] + q0v[e], 0.f));
            af1[e] = f2bf(fmaxf(p[e] + q1v[e], 0.f));
        }

        const s16x8* bfp = (const s16x8*)W2f + (size_t)(kk * 7) * 64 + lane;
#pragma unroll
        for (int t = 0; t < 7; ++t) {
            s16x8 bf = bfp[(size_t)t * 64];
            acc[0][t] = __builtin_amdgcn_mfma_f32_16x16x32_bf16(af0, bf, acc[0][t], 0, 0, 0);
            acc[1][t] = __builtin_amdgcn_mfma_f32_16x16x32_bf16(af1, bf, acc[1][t], 0, 0, 0);
        }
        __syncthreads();
    }

    float bias[7];
#pragma unroll
    for (int t = 0; t < 7; ++t) {
        int l = t * 16 + l15;
        bias[t] = (l < L_) ? b2[l] : 0.f;
    }

#pragma unroll
    for (int ii = 0; ii < 2; ++ii) {
        const size_t obase = (size_t)(b * N_ + (i0 + ii)) * N_ * L_;
#pragma unroll
        for (int r = 0; r < 4; ++r) {
            int j = j0 + g * 4 + r;
            float* op = out + obase + (size_t)j * L_;
#pragma unroll
            for (int t = 0; t < 7; ++t) {
                int l = t * 16 + l15;
                if (l < L_) op[l] = acc[ii][t][r] + bias[t];
            }
        }
    }
}

// ---------------------------------------------------------------------------
extern "C" void kernel_launch(void* const* d_in, const int* in_sizes, int n_in,
                              void* d_out, int out_size, void* d_ws, size_t ws_size,
                              hipStream_t stream)
{
    const float* repr = (const float*)d_in[0];
    const float* W1   = (const float*)d_in[1];
    const float* b1   = (const float*)d_in[2];
    const float* W2   = (const float*)d_in[3];
    const float* b2   = (const float*)d_in[4];
    float* out = (float*)d_out;

    char* ws = (char*)d_ws;
    float* Pt  = (float*)(ws);                         // 1572864 B (transposed layout)
    float* Qm  = (float*)(ws + 1572864);               // 1572864 B
    short* W1f = (short*)(ws + 3145728);               // 1179648 B
    short* W2f = (short*)(ws + 4325376);               // 86016 B

    hipLaunchKernelGGL(prep_w1f,  dim3(288),  dim3(256), 0, stream, W1, W1f);
    hipLaunchKernelGGL(prep_w2f,  dim3(21),   dim3(256), 0, stream, W2, W2f);
    hipLaunchKernelGGL(pq_gemm,   dim3(768),  dim3(256), 0, stream, repr, W1f, b1, Pt, Qm);
    hipLaunchKernelGGL(fused_out, dim3(1024), dim3(256), 0, stream, Pt, Qm, W2f, b2, out);
}

// Round 5
// 108.127 us; speedup vs baseline: 1.3643x; 1.1381x over previous
//
#include <hip/hip_runtime.h>
#include <hip/hip_bf16.h>

#define B_   8
#define N_   128
#define H_   768
#define HID_ 384
#define L_   100

typedef float f32x4 __attribute__((ext_vector_type(4)));
typedef short s16x8 __attribute__((ext_vector_type(8)));

__device__ __forceinline__ short f2bf(float f) {
    __hip_bfloat16 h = __float2bfloat16(f);
    return __builtin_bit_cast(short, h);
}

// async global->LDS, 16 B per lane. LDS dest = wave-uniform base (+lane*16 by HW);
// global src is per-lane.
__device__ __forceinline__ void gl_lds16(const void* g, void* l) {
    __builtin_amdgcn_global_load_lds(
        (const __attribute__((address_space(1))) unsigned int*)g,
        (__attribute__((address_space(3))) unsigned int*)l, 16, 0, 0);
}

// ---------------------------------------------------------------------------
// Prep: W1 (1536x384 fp32) -> MFMA-B fragments bf16.
// W1f[ct 0..47][kk 0..23][lane][e]: col c = ct*16+(lane&15), k = kk*32+(lane>>4)*8+e
// ---------------------------------------------------------------------------
__global__ void prep_w1f(const float* __restrict__ W1, short* __restrict__ W1f) {
    int tid = blockIdx.x * 256 + threadIdx.x;
    if (tid >= 48 * 24 * 64) return;
    int lane = tid & 63;
    int kk   = (tid >> 6) % 24;
    int ct   = tid / (24 * 64);
    int c    = ct * 16 + (lane & 15);
    int k0   = kk * 32 + ((lane >> 4) << 3);
    short v[8];
#pragma unroll
    for (int e = 0; e < 8; ++e) {
        int k = k0 + e;
        float f = (c < HID_) ? W1[(size_t)k * HID_ + c]
                             : W1[(size_t)(H_ + k) * HID_ + (c - HID_)];
        v[e] = f2bf(f);
    }
    ((s16x8*)W1f)[tid] = *(const s16x8*)v;
}

// ---------------------------------------------------------------------------
// Prep: W2 (384x100 fp32) -> MFMA-B fragments bf16, L padded to 112.
// W2f[kk 0..11][t 0..6][lane][e]
// ---------------------------------------------------------------------------
__global__ void prep_w2f(const float* __restrict__ W2, short* __restrict__ W2f) {
    int tid = blockIdx.x * 256 + threadIdx.x;
    if (tid >= 12 * 7 * 64) return;
    int lane = tid & 63;
    int t    = (tid >> 6) % 7;
    int kk   = tid / (7 * 64);
    int c    = t * 16 + (lane & 15);
    int k0   = kk * 32 + ((lane >> 4) << 3);
    short v[8];
#pragma unroll
    for (int e = 0; e < 8; ++e) {
        float f = (c < L_) ? W2[(size_t)(k0 + e) * L_ + c] : 0.0f;
        v[e] = f2bf(f);
    }
    ((s16x8*)W2f)[tid] = *(const s16x8*)v;
}

// ---------------------------------------------------------------------------
// pq_gemm: P(+b1) and Q from repr @ W1, MFMA. A staged to LDS via gl_lds.
// P written TRANSPOSED: Pt[b][slice 0..11][u 0..7][row 0..127][e4 0..3]
// (slice = 32 hid-cols, contiguous 16 KB per slice) so fused_out stages
// kk-slices with fully contiguous gl_lds. Q row-major [1024][384].
// ---------------------------------------------------------------------------
__global__ __launch_bounds__(256) void pq_gemm(
    const float* __restrict__ repr, const short* __restrict__ W1f,
    const float* __restrict__ b1,
    float* __restrict__ Pt, float* __restrict__ Q)
{
    __shared__ float atile[192 * 16 * 4];   // 49152 B
    const int rt   = blockIdx.x / 12;
    const int cg   = blockIdx.x % 12;
    const int w    = threadIdx.x >> 6;
    const int lane = threadIdx.x & 63;
    const int l15  = lane & 15;
    const int g    = lane >> 4;
    const int ct   = cg * 4 + w;
    const int row_g0 = rt * 16;

#pragma unroll
    for (int c = 0; c < 12; ++c) {
        int call = w * 12 + c;
        const float* src = repr + (size_t)(row_g0 + (lane & 15)) * H_
                         + (call * 4 + (lane >> 4)) * 4;
        gl_lds16(src, (char*)atile + call * 1024);
    }
    __syncthreads();

    f32x4 acc;
    acc[0] = 0.f; acc[1] = 0.f; acc[2] = 0.f; acc[3] = 0.f;
    const s16x8* bbase = (const s16x8*)W1f + (size_t)(ct * 24) * 64 + lane;

#pragma unroll 4
    for (int kk = 0; kk < 24; ++kk) {
        const int u0 = kk * 8 + g * 2;
        float a[8];
        *(float4*)&a[0] = *(const float4*)&atile[(u0 * 16 + l15) * 4];
        *(float4*)&a[4] = *(const float4*)&atile[((u0 + 1) * 16 + l15) * 4];
        s16x8 af;
#pragma unroll
        for (int e = 0; e < 8; ++e) af[e] = f2bf(a[e]);
        s16x8 bf = bbase[(size_t)kk * 64];
        acc = __builtin_amdgcn_mfma_f32_16x16x32_bf16(af, bf, acc, 0, 0, 0);
    }

    const int b = rt >> 3;
    const int c = ct * 16 + l15;
#pragma unroll
    for (int r = 0; r < 4; ++r) {
        int brow = (rt & 7) * 16 + g * 4 + r;
        float v = acc[r];
        if (c < HID_) {
            int slice = c >> 5, un = (c & 31) >> 2, e4 = c & 3;
            Pt[((((size_t)b * 12 + slice) * 8 + un) * 128 + brow) * 4 + e4] = v + b1[c];
        } else {
            Q[(size_t)(b * N_ + brow) * HID_ + (c - HID_)] = v;
        }
    }
}

// ---------------------------------------------------------------------------
// fused_out: out[b,i,j,l] = relu(P[b,j,:]+Q[b,i,:]) . W2 + b2
// Grid 512: blk -> (b = blk>>6, i0 = (blk&63)*2). 512 thr = 8 waves; wave w
// owns j in [w*16, +16), 2 i each, 7 L-tiles. ALL in-loop data via gl_lds
// double-buffer: per kk stage next Pt slice (16 KB) + next W2f slab (7 KB);
// Q staged once. Zero direct global loads in the loop. Epilogue: acc ->
// wave-private LDS (stride-114) -> one contiguous 400 B float2 row-store.
// ---------------------------------------------------------------------------
__global__ __launch_bounds__(512, 4) void fused_out(
    const float* __restrict__ Pt, const float* __restrict__ Q,
    const short* __restrict__ W2f, const float* __restrict__ b2,
    float* __restrict__ out)
{
    __shared__ __align__(16) char smem[58368];
    char* pbufB  = smem;               // 2 x 16384 B  (Pt slice dbuf)
    char* w2bufB = smem + 32768;       // 2 x 7168 B   (W2f slab dbuf)
    char* qldsB  = smem + 47104;       // 3072 B       (2 Q rows)
    float* storeF = (float*)smem;      // epilogue overlay: [8 waves][16*114]

    const int blk  = blockIdx.x;
    const int b    = blk >> 6;
    const int i0   = (blk & 63) << 1;
    const int w    = threadIdx.x >> 6;
    const int lane = threadIdx.x & 63;
    const int l15  = lane & 15;
    const int g    = lane >> 4;

    const char* ptb = (const char*)Pt + (size_t)b * 12 * 16384;
    const char* w2g = (const char*)W2f;

    // ---- prologue: stage kk=0 Pt + W2f, and Q ----
    gl_lds16(ptb + w * 2048 + lane * 16,        pbufB + w * 2048);
    gl_lds16(ptb + w * 2048 + 1024 + lane * 16, pbufB + w * 2048 + 1024);
    if (w < 7)
        gl_lds16(w2g + w * 1024 + lane * 16, w2bufB + w * 1024);
    if (w == 7) {
        const char* qsrc = (const char*)(Q + (size_t)(b * N_ + i0) * HID_);
#pragma unroll
        for (int c2 = 0; c2 < 3; ++c2)
            gl_lds16(qsrc + c2 * 1024 + lane * 16, qldsB + c2 * 1024);
    }
    __syncthreads();

    f32x4 acc[2][7];
#pragma unroll
    for (int ii = 0; ii < 2; ++ii)
#pragma unroll
        for (int t = 0; t < 7; ++t) {
            acc[ii][t][0] = 0.f; acc[ii][t][1] = 0.f;
            acc[ii][t][2] = 0.f; acc[ii][t][3] = 0.f;
        }

    const float* qF = (const float*)qldsB;

#pragma unroll
    for (int kk = 0; kk < 12; ++kk) {
        const int cur = kk & 1;
        if (kk < 11) {
            const char* src = ptb + (size_t)(kk + 1) * 16384 + w * 2048;
            char* dst = pbufB + (cur ^ 1) * 16384 + w * 2048;
            gl_lds16(src + lane * 16,        dst);
            gl_lds16(src + 1024 + lane * 16, dst + 1024);
            if (w < 7)
                gl_lds16(w2g + (size_t)((kk + 1) * 7 + w) * 1024 + lane * 16,
                         w2bufB + (cur ^ 1) * 7168 + w * 1024);
        }

        const float* pF = (const float*)(pbufB + cur * 16384);
        float p[8], q0v[8], q1v[8];
        *(float4*)&p[0] = *(const float4*)&pF[((g * 2 + 0) * 128 + w * 16 + l15) * 4];
        *(float4*)&p[4] = *(const float4*)&pF[((g * 2 + 1) * 128 + w * 16 + l15) * 4];
        *(float4*)&q0v[0] = *(const float4*)&qF[0 * HID_ + kk * 32 + g * 8];
        *(float4*)&q0v[4] = *(const float4*)&qF[0 * HID_ + kk * 32 + g * 8 + 4];
        *(float4*)&q1v[0] = *(const float4*)&qF[1 * HID_ + kk * 32 + g * 8];
        *(float4*)&q1v[4] = *(const float4*)&qF[1 * HID_ + kk * 32 + g * 8 + 4];

        s16x8 af0, af1;
#pragma unroll
        for (int e = 0; e < 8; ++e) {
            af0[e] = f2bf(fmaxf(p[e] + q0v[e], 0.f));
            af1[e] = f2bf(fmaxf(p[e] + q1v[e], 0.f));
        }

        const s16x8* bfp = (const s16x8*)(w2bufB + cur * 7168) + lane;
#pragma unroll
        for (int t = 0; t < 7; ++t) {
            s16x8 bf = bfp[(size_t)t * 64];
            acc[0][t] = __builtin_amdgcn_mfma_f32_16x16x32_bf16(af0, bf, acc[0][t], 0, 0, 0);
            acc[1][t] = __builtin_amdgcn_mfma_f32_16x16x32_bf16(af1, bf, acc[1][t], 0, 0, 0);
        }
        __syncthreads();
    }

    // ---- epilogue: bias, LDS transpose (wave-private), coalesced stores ----
    float bias[7];
#pragma unroll
    for (int t = 0; t < 7; ++t) {
        int l = t * 16 + l15;
        bias[t] = (l < L_) ? b2[l] : 0.f;
    }

    __syncthreads();   // all waves done with pbuf/w2buf; reuse as store staging
    float* srow = storeF + w * (16 * 114);

#pragma unroll
    for (int ii = 0; ii < 2; ++ii) {
#pragma unroll
        for (int t = 0; t < 7; ++t)
#pragma unroll
            for (int r = 0; r < 4; ++r)
                srow[(g * 4 + r) * 114 + t * 16 + l15] = acc[ii][t][r] + bias[t];
        // wave-private region: compiler orders ds ops via lgkmcnt, no barrier
        const size_t obase = (size_t)(b * N_ + (i0 + ii)) * N_ * L_;
#pragma unroll
        for (int row = 0; row < 16; ++row) {
            if (lane < 50) {
                float2 v = *(const float2*)&srow[row * 114 + lane * 2];
                *(float2*)(out + obase + (size_t)(w * 16 + row) * L_ + lane * 2) = v;
            }
        }
    }
}

// ---------------------------------------------------------------------------
extern "C" void kernel_launch(void* const* d_in, const int* in_sizes, int n_in,
                              void* d_out, int out_size, void* d_ws, size_t ws_size,
                              hipStream_t stream)
{
    const float* repr = (const float*)d_in[0];
    const float* W1   = (const float*)d_in[1];
    const float* b1   = (const float*)d_in[2];
    const float* W2   = (const float*)d_in[3];
    const float* b2   = (const float*)d_in[4];
    float* out = (float*)d_out;

    char* ws = (char*)d_ws;
    float* Pt  = (float*)(ws);                         // 1572864 B (transposed layout)
    float* Qm  = (float*)(ws + 1572864);               // 1572864 B
    short* W1f = (short*)(ws + 3145728);               // 1179648 B
    short* W2f = (short*)(ws + 4325376);               // 86016 B

    hipLaunchKernelGGL(prep_w1f,  dim3(288), dim3(256), 0, stream, W1, W1f);
    hipLaunchKernelGGL(prep_w2f,  dim3(21),  dim3(256), 0, stream, W2, W2f);
    hipLaunchKernelGGL(pq_gemm,   dim3(768), dim3(256), 0, stream, repr, W1f, b1, Pt, Qm);
    hipLaunchKernelGGL(fused_out, dim3(512), dim3(512), 0, stream, Pt, Qm, W2f, b2, out);
}